// Round 1
// baseline (109.217 us; speedup 1.0000x reference)
//
#include <hip/hip_runtime.h>
#include <math.h>

typedef _Float16 half8  __attribute__((ext_vector_type(8)));
typedef _Float16 half4v __attribute__((ext_vector_type(4)));
typedef float    float4v __attribute__((ext_vector_type(4)));

#define BM   128
#define KDIM 256
#define WSTR 264     // W1 LDS row stride in halves: 256 + 8 pad; 528 B == 4 dwords mod 32 banks -> 2-way (free)
#define HSW  65      // fp32 h-tile stride: (r+k)%32 -> 2-way (free)

__global__ __launch_bounds__(256, 2)
void qc_fused(const float* __restrict__ x,
              const float* __restrict__ W1,
              const float* __restrict__ b1,
              const float* __restrict__ W2,
              const float* __restrict__ b2,
              const float* __restrict__ qw,
              float* __restrict__ out)
{
    __shared__ _Float16 wh[64 * WSTR];   // 33792 B: full W1 (64 x 256) fp16, staged ONCE
    __shared__ float hs[BM * HSW];       // 33280 B: post-ReLU h tile
    __shared__ float w2s[256];
    __shared__ float b1s[64];
    __shared__ float b2s[4];
    __shared__ float trig[32];           // [layer][qubit][{cy,sy,cz,sz}]

    const int tid  = threadIdx.x;
    const int lane = tid & 63;
    const int wv   = tid >> 6;           // wave 0..3 -> rows wv*32..wv*32+31
    const int m    = lane & 15;
    const int q    = lane >> 4;
    const int row0 = blockIdx.x * BM;

    // ---- one-time per-block setup (before the single stage barrier) ----
    w2s[tid] = W2[tid];                  // 4*64 = 256
    if (tid < 64) b1s[tid] = b1[tid];
    if (tid < 4)  b2s[tid] = b2[tid];
    if (tid < 8) {
        int l = tid >> 2, i = tid & 3;
        float wy = qw[(l * 4 + i) * 2 + 0];
        float wz = qw[(l * 4 + i) * 2 + 1];
        float sy, cy, sz, cz;
        sincosf(0.5f * wy, &sy, &cy);
        sincosf(0.5f * wz, &sz, &cz);
        trig[(l * 4 + i) * 4 + 0] = cy;
        trig[(l * 4 + i) * 4 + 1] = sy;
        trig[(l * 4 + i) * 4 + 2] = cz;
        trig[(l * 4 + i) * 4 + 3] = sz;
    }

    // ---- stage full W1 (fp32 -> fp16) once: thread t does row t>>2, 64-col quarter t&3 ----
    {
        const int wr = tid >> 2;
        const int c0 = (tid & 3) * 64;
        const float* wp = W1 + (size_t)wr * KDIM + c0;
        _Float16* dst = &wh[wr * WSTR + c0];
        #pragma unroll
        for (int j = 0; j < 16; ++j) {
            float4v v = *(const float4v*)(wp + 4 * j);
            half4v h;
            h[0] = (_Float16)v[0]; h[1] = (_Float16)v[1];
            h[2] = (_Float16)v[2]; h[3] = (_Float16)v[3];
            *(half4v*)(dst + 4 * j) = h;
        }
    }
    __syncthreads();   // barrier #1 (only one before the tail barrier)

    // ---- GEMM1: A-fragments straight from global (no LDS round-trip), B from wh ----
    float4v acc[2][4] = {};              // 2 row-tiles x 4 col-tiles, fp32
    const float* xp0 = x + (size_t)(row0 + wv * 32 + m) * KDIM;
    const float* xp1 = xp0 + 16 * KDIM;

    #pragma unroll
    for (int ks = 0; ks < 8; ++ks) {
        const int kf = ks * 32 + q * 8;  // this lane's 8-float slice of K
        float4v a0l = *(const float4v*)(xp0 + kf);
        float4v a0h = *(const float4v*)(xp0 + kf + 4);
        float4v a1l = *(const float4v*)(xp1 + kf);
        float4v a1h = *(const float4v*)(xp1 + kf + 4);
        half8 af0, af1;
        af0[0] = (_Float16)a0l[0]; af0[1] = (_Float16)a0l[1];
        af0[2] = (_Float16)a0l[2]; af0[3] = (_Float16)a0l[3];
        af0[4] = (_Float16)a0h[0]; af0[5] = (_Float16)a0h[1];
        af0[6] = (_Float16)a0h[2]; af0[7] = (_Float16)a0h[3];
        af1[0] = (_Float16)a1l[0]; af1[1] = (_Float16)a1l[1];
        af1[2] = (_Float16)a1l[2]; af1[3] = (_Float16)a1l[3];
        af1[4] = (_Float16)a1h[0]; af1[5] = (_Float16)a1h[1];
        af1[6] = (_Float16)a1h[2]; af1[7] = (_Float16)a1h[3];
        #pragma unroll
        for (int b = 0; b < 4; ++b) {
            half8 bf = *(const half8*)&wh[(16 * b + m) * WSTR + kf];
            acc[0][b] = __builtin_amdgcn_mfma_f32_16x16x32_f16(af0, bf, acc[0][b], 0, 0, 0);
            acc[1][b] = __builtin_amdgcn_mfma_f32_16x16x32_f16(af1, bf, acc[1][b], 0, 0, 0);
        }
    }

    // ---- epilogue: bias + relu -> hs (no barrier needed before: fresh buffer) ----
    #pragma unroll
    for (int a = 0; a < 2; ++a) {
        #pragma unroll
        for (int b = 0; b < 4; ++b) {
            #pragma unroll
            for (int i = 0; i < 4; ++i) {
                int row = wv * 32 + 16 * a + 4 * q + i;   // C/D: row = quad*4+reg
                int col = 16 * b + m;                     //      col = lane&15
                float v = acc[a][b][i] + b1s[col];
                hs[row * HSW + col] = fmaxf(v, 0.0f);
            }
        }
    }
    __syncthreads();   // barrier #2

    // ---- GEMM2 + tanh + quantum circuit: one thread per row ----
    if (tid < BM) {
        const int r = tid;
        float s0 = b2s[0], s1 = b2s[1], s2 = b2s[2], s3 = b2s[3];
        #pragma unroll 8
        for (int k = 0; k < 64; ++k) {
            float hv = hs[r * HSW + k];       // (r+k)%32 -> 2-way, free
            s0 = fmaf(hv, w2s[0 * 64 + k], s0);   // w2s broadcast, free
            s1 = fmaf(hv, w2s[1 * 64 + k], s1);
            s2 = fmaf(hv, w2s[2 * 64 + k], s2);
            s3 = fmaf(hv, w2s[3 * 64 + k], s3);
        }
        float ang[4] = { tanhf(s0), tanhf(s1), tanhf(s2), tanhf(s3) };

        float ca[4], sa[4];
        #pragma unroll
        for (int i = 0; i < 4; ++i)
            __sincosf(0.5f * ang[i], &sa[i], &ca[i]);

        // state idx = w0*8 + w1*4 + w2*2 + w3
        float re[16], im[16];
        #pragma unroll
        for (int idx = 0; idx < 16; ++idx) {
            re[idx] = (idx & 8 ? sa[0] : ca[0]) * (idx & 4 ? sa[1] : ca[1]) *
                      (idx & 2 ? sa[2] : ca[2]) * (idx & 1 ? sa[3] : ca[3]);
            im[idx] = 0.0f;
        }
        #pragma unroll
        for (int l = 0; l < 2; ++l) {
            #pragma unroll
            for (int i = 0; i < 4; ++i) {
                const float cy = trig[(l * 4 + i) * 4 + 0];
                const float sy = trig[(l * 4 + i) * 4 + 1];
                const float cz = trig[(l * 4 + i) * 4 + 2];
                const float sz = trig[(l * 4 + i) * 4 + 3];
                const int mq = 8 >> i;
                #pragma unroll
                for (int idx = 0; idx < 16; ++idx) {
                    if (!(idx & mq)) {
                        int j = idx | mq;
                        float ar = re[idx], ai = im[idx], br = re[j], bi = im[j];
                        re[idx] = fmaf(cy, ar, -sy * br);
                        im[idx] = fmaf(cy, ai, -sy * bi);
                        re[j]   = fmaf(sy, ar,  cy * br);
                        im[j]   = fmaf(sy, ai,  cy * bi);
                    }
                }
                #pragma unroll
                for (int idx = 0; idx < 16; ++idx) {
                    float sgn = (idx & mq) ? sz : -sz;
                    float ar = re[idx], ai = im[idx];
                    re[idx] = fmaf(ar, cz, -ai * sgn);
                    im[idx] = fmaf(ar, sgn, ai * cz);
                }
            }
            #pragma unroll
            for (int c = 0; c < 4; ++c) {
                int t  = (c + 1) & 3;
                int mc = 8 >> c, mt = 8 >> t;
                #pragma unroll
                for (int idx = 0; idx < 16; ++idx) {
                    if ((idx & mc) && !(idx & mt)) {
                        int j = idx | mt;
                        float tr = re[idx]; re[idx] = re[j]; re[j] = tr;
                        float ti = im[idx]; im[idx] = im[j]; im[j] = ti;
                    }
                }
            }
        }
        float z = 0.0f;
        #pragma unroll
        for (int idx = 0; idx < 16; ++idx) {
            float p = re[idx] * re[idx] + im[idx] * im[idx];
            z += (idx & 8) ? -p : p;
        }
        out[row0 + r] = z;
    }
}

extern "C" void kernel_launch(void* const* d_in, const int* in_sizes, int n_in,
                              void* d_out, int out_size, void* d_ws, size_t ws_size,
                              hipStream_t stream) {
    const float* x  = (const float*)d_in[0];
    const float* W1 = (const float*)d_in[1];
    const float* b1 = (const float*)d_in[2];
    const float* W2 = (const float*)d_in[3];
    const float* b2 = (const float*)d_in[4];
    const float* qw = (const float*)d_in[5];
    float* out = (float*)d_out;
    const int B = in_sizes[0] / KDIM;   // 65536
    qc_fused<<<B / BM, 256, 0, stream>>>(x, W1, b1, W2, b2, qw, out);
}

// Round 3
// 105.595 us; speedup vs baseline: 1.0343x; 1.0343x over previous
//
#include <hip/hip_runtime.h>
#include <math.h>

typedef _Float16 half8  __attribute__((ext_vector_type(8)));
typedef _Float16 half4v __attribute__((ext_vector_type(4)));
typedef float    float4v __attribute__((ext_vector_type(4)));

#define BM   128
#define KDIM 256
#define CH   64          // k-chunk (floats)
#define NCH  4           // KDIM / CH
#define XBS  72          // per-wave x buffer row stride (halves): 64+8 pad -> 144 B, balanced banks
#define WSTR 264         // W1 LDS row stride (halves): 256+8 pad
#define HSW  65          // fp32 h-tile stride: (r+k)%32 -> 2-way (free)

__global__ __launch_bounds__(256, 2)
void qc_fused(const float* __restrict__ x,
              const float* __restrict__ W1,
              const float* __restrict__ b1,
              const float* __restrict__ W2,
              const float* __restrict__ b2,
              const float* __restrict__ qw,
              float* __restrict__ out)
{
    __shared__ _Float16 wh[64 * WSTR];        // 33792 B; overlaid by fp32 hs after GEMM1
    __shared__ _Float16 xb[4 * 2 * 32 * XBS]; // 36864 B: per-wave double-buffered x tiles
    __shared__ float w2s[256];
    __shared__ float b1s[64];
    __shared__ float b2s[4];
    __shared__ float trig[32];                // [layer][qubit][{cy,sy,cz,sz}]

    const int tid  = threadIdx.x;
    const int lane = tid & 63;
    const int wv   = tid >> 6;                // wave 0..3 -> rows wv*32..wv*32+31
    const int m    = lane & 15;
    const int q    = lane >> 4;
    const int row0 = blockIdx.x * BM;

    // ---- one-time per-block setup (before the single stage barrier) ----
    w2s[tid] = W2[tid];
    if (tid < 64) b1s[tid] = b1[tid];
    if (tid < 4)  b2s[tid] = b2[tid];
    if (tid < 8) {
        int l = tid >> 2, i = tid & 3;
        float wy = qw[(l * 4 + i) * 2 + 0];
        float wz = qw[(l * 4 + i) * 2 + 1];
        float sy, cy, sz, cz;
        sincosf(0.5f * wy, &sy, &cy);
        sincosf(0.5f * wz, &sz, &cz);
        trig[(l * 4 + i) * 4 + 0] = cy;
        trig[(l * 4 + i) * 4 + 1] = sy;
        trig[(l * 4 + i) * 4 + 2] = cz;
        trig[(l * 4 + i) * 4 + 3] = sz;
    }

    // ---- stage full W1 (fp32 -> fp16) once: thread t does row t>>2, 64-col quarter t&3 ----
    {
        const int wr = tid >> 2;
        const int c0 = (tid & 3) * 64;
        const float* wp = W1 + (size_t)wr * KDIM + c0;
        _Float16* dst = &wh[wr * WSTR + c0];
        #pragma unroll
        for (int j = 0; j < 16; ++j) {
            float4v v = *(const float4v*)(wp + 4 * j);
            half4v h;
            h[0] = (_Float16)v[0]; h[1] = (_Float16)v[1];
            h[2] = (_Float16)v[2]; h[3] = (_Float16)v[3];
            *(half4v*)(dst + 4 * j) = h;
        }
    }

    // ---- x staging geometry: per round, lanes cover 4 rows x 64 floats, coalesced (8 lines/instr)
    const float* xw = x + (size_t)(row0 + wv * 32) * KDIM;   // this wave's 32 rows
    _Float16* xbw = &xb[wv * (2 * 32 * XBS)];                // this wave's private dbuf
    const int srow = lane >> 4;          // 0..3
    const int scol = (lane & 15) * 4;    // float col 0..60

    // prologue: issue chunk-0 loads (latency hides under W1 staging + barrier)
    float4v xr[8];
    #pragma unroll
    for (int t = 0; t < 8; ++t)
        xr[t] = *(const float4v*)(xw + (size_t)(4 * t + srow) * KDIM + scol);

    __syncthreads();   // barrier #1: W1 resident (the ONLY pre-tail block barrier)

    // write chunk 0 into buffer 0 (wave-private; vmcnt waits inserted by compiler)
    #pragma unroll
    for (int t = 0; t < 8; ++t) {
        half4v h;
        h[0] = (_Float16)xr[t][0]; h[1] = (_Float16)xr[t][1];
        h[2] = (_Float16)xr[t][2]; h[3] = (_Float16)xr[t][3];
        *(half4v*)&xbw[(4 * t + srow) * XBS + scol] = h;
    }

    // ---- GEMM1 main loop: per-wave double-buffered, ZERO block barriers ----
    float4v acc[2][4] = {};
    #pragma unroll
    for (int c = 0; c < NCH; ++c) {
        // issue next chunk's global loads first (stay in flight during MFMAs)
        if (c + 1 < NCH) {
            #pragma unroll
            for (int t = 0; t < 8; ++t)
                xr[t] = *(const float4v*)(xw + (size_t)(4 * t + srow) * KDIM
                                          + (c + 1) * CH + scol);
        }
        // compute chunk c from buffer c&1 (wave-internal lgkmcnt ordering only)
        const _Float16* bufc = &xbw[(c & 1) * (32 * XBS)];
        #pragma unroll
        for (int ks = 0; ks < 2; ++ks) {
            const int ko = ks * 32 + q * 8;
            half8 af0 = *(const half8*)&bufc[m * XBS + ko];
            half8 af1 = *(const half8*)&bufc[(16 + m) * XBS + ko];
            #pragma unroll
            for (int b = 0; b < 4; ++b) {
                half8 bf = *(const half8*)&wh[(16 * b + m) * WSTR + c * CH + ko];
                acc[0][b] = __builtin_amdgcn_mfma_f32_16x16x32_f16(af0, bf, acc[0][b], 0, 0, 0);
                acc[1][b] = __builtin_amdgcn_mfma_f32_16x16x32_f16(af1, bf, acc[1][b], 0, 0, 0);
            }
        }
        // convert + write next chunk into the other buffer
        if (c + 1 < NCH) {
            _Float16* nb = &xbw[((c + 1) & 1) * (32 * XBS)];
            #pragma unroll
            for (int t = 0; t < 8; ++t) {
                half4v h;
                h[0] = (_Float16)xr[t][0]; h[1] = (_Float16)xr[t][1];
                h[2] = (_Float16)xr[t][2]; h[3] = (_Float16)xr[t][3];
                *(half4v*)&nb[(4 * t + srow) * XBS + scol] = h;
            }
        }
    }

    __syncthreads();   // barrier #2: all waves done reading wh -> safe to overlay hs

    // ---- epilogue: bias + relu -> hs (fp32, overlaid on wh) ----
    float* hs = (float*)wh;
    #pragma unroll
    for (int a = 0; a < 2; ++a) {
        #pragma unroll
        for (int b = 0; b < 4; ++b) {
            #pragma unroll
            for (int i = 0; i < 4; ++i) {
                int row = wv * 32 + 16 * a + 4 * q + i;   // C/D: row = quad*4+reg
                int col = 16 * b + m;                     //      col = lane&15
                float v = acc[a][b][i] + b1s[col];
                hs[row * HSW + col] = fmaxf(v, 0.0f);
            }
        }
    }
    __syncthreads();   // barrier #3

    // ---- GEMM2 + tanh + quantum circuit: one thread per row ----
    if (tid < BM) {
        const int r = tid;
        float s0 = b2s[0], s1 = b2s[1], s2 = b2s[2], s3 = b2s[3];
        #pragma unroll 8
        for (int k = 0; k < 64; ++k) {
            float hv = hs[r * HSW + k];       // (r+k)%32 -> 2-way, free
            s0 = fmaf(hv, w2s[0 * 64 + k], s0);   // w2s broadcast, free
            s1 = fmaf(hv, w2s[1 * 64 + k], s1);
            s2 = fmaf(hv, w2s[2 * 64 + k], s2);
            s3 = fmaf(hv, w2s[3 * 64 + k], s3);
        }
        float ang[4] = { tanhf(s0), tanhf(s1), tanhf(s2), tanhf(s3) };

        float ca[4], sa[4];
        #pragma unroll
        for (int i = 0; i < 4; ++i)
            __sincosf(0.5f * ang[i], &sa[i], &ca[i]);

        // state idx = w0*8 + w1*4 + w2*2 + w3
        float re[16], im[16];
        #pragma unroll
        for (int idx = 0; idx < 16; ++idx) {
            re[idx] = (idx & 8 ? sa[0] : ca[0]) * (idx & 4 ? sa[1] : ca[1]) *
                      (idx & 2 ? sa[2] : ca[2]) * (idx & 1 ? sa[3] : ca[3]);
            im[idx] = 0.0f;
        }
        #pragma unroll
        for (int l = 0; l < 2; ++l) {
            #pragma unroll
            for (int i = 0; i < 4; ++i) {
                const float cy = trig[(l * 4 + i) * 4 + 0];
                const float sy = trig[(l * 4 + i) * 4 + 1];
                const float cz = trig[(l * 4 + i) * 4 + 2];
                const float sz = trig[(l * 4 + i) * 4 + 3];
                const int mq = 8 >> i;
                #pragma unroll
                for (int idx = 0; idx < 16; ++idx) {
                    if (!(idx & mq)) {
                        int j = idx | mq;
                        float ar = re[idx], ai = im[idx], br = re[j], bi = im[j];
                        re[idx] = fmaf(cy, ar, -sy * br);
                        im[idx] = fmaf(cy, ai, -sy * bi);
                        re[j]   = fmaf(sy, ar,  cy * br);
                        im[j]   = fmaf(sy, ai,  cy * bi);
                    }
                }
                #pragma unroll
                for (int idx = 0; idx < 16; ++idx) {
                    float sgn = (idx & mq) ? sz : -sz;
                    float ar = re[idx], ai = im[idx];
                    re[idx] = fmaf(ar, cz, -ai * sgn);
                    im[idx] = fmaf(ar, sgn, ai * cz);
                }
            }
            #pragma unroll
            for (int c = 0; c < 4; ++c) {
                int t  = (c + 1) & 3;
                int mc = 8 >> c, mt = 8 >> t;
                #pragma unroll
                for (int idx = 0; idx < 16; ++idx) {
                    if ((idx & mc) && !(idx & mt)) {
                        int j = idx | mt;
                        float tr = re[idx]; re[idx] = re[j]; re[j] = tr;
                        float ti = im[idx]; im[idx] = im[j]; im[j] = ti;
                    }
                }
            }
        }
        float z = 0.0f;
        #pragma unroll
        for (int idx = 0; idx < 16; ++idx) {
            float p = re[idx] * re[idx] + im[idx] * im[idx];
            z += (idx & 8) ? -p : p;
        }
        out[row0 + r] = z;
    }
}

extern "C" void kernel_launch(void* const* d_in, const int* in_sizes, int n_in,
                              void* d_out, int out_size, void* d_ws, size_t ws_size,
                              hipStream_t stream) {
    const float* x  = (const float*)d_in[0];
    const float* W1 = (const float*)d_in[1];
    const float* b1 = (const float*)d_in[2];
    const float* W2 = (const float*)d_in[3];
    const float* b2 = (const float*)d_in[4];
    const float* qw = (const float*)d_in[5];
    float* out = (float*)d_out;
    const int B = in_sizes[0] / KDIM;   // 65536
    qc_fused<<<B / BM, 256, 0, stream>>>(x, W1, b1, W2, b2, qw, out);
}